// Round 9
// baseline (3457.657 us; speedup 1.0000x reference)
//
#include <hip/hip_runtime.h>

// ---------------------------------------------------------------------------
// PointNet++ (defense variant) forward on MI355X.
// B=8, N=4096 -> 2048 -> 512, K=32 neighbors. Geometry is EXACT: positions are
// multiples of 2^-23 (f64 knn d2 / i64 fps d2 are exact) — discrete choices
// match an np-f64 reference exactly.
// R16: cell-sort + per-thread bbox wave-skip: stage1 1578 -> 1363us (BEST).
// R17-R19: column-skip / Morton / paired-batch regressed -> reverted.
// R20: stage3 sRed-in-h1s alias (3 blk/CU): null, harmless, kept.
// R21: LDS mailbox sync: 2022us REGRESSED (+550cyc/iter polling cost) ->
// s_barrier is cheap; per-iter cost is distributed. Sync replacement CLOSED.
// R22: exact dual-selection speculation. Each wave publishes top-2 keys +
// positions. Post-barrier: global (K1,K2) exact; since minds only DECREASE
// and all non-K1 minds <= K2, the single exact check
//   d2(K2elem, K1elem) >= d2(K2)
// proves K2's mind unchanged by K1's update => next argmax == K2 => commit
// TWO selections this round (update both centers), halving sync rounds.
// Check fails -> single selection (R16-identical). Bit-exact either way.
// ---------------------------------------------------------------------------

#define NB 8

__device__ __forceinline__ unsigned obits(float f) {
  unsigned u = __float_as_uint(f);
  return (u & 0x80000000u) ? ~u : (u | 0x80000000u);
}

static constexpr int CAND = 1024;

// ---------------- DPP helpers (VALU cross-lane, no LDS pipe) ----------------
template<int CTRL>
__device__ __forceinline__ unsigned long long dpp_max_step(unsigned long long v) {
  const int lo = (int)(unsigned)(v & 0xffffffffull);
  const int hi = (int)(unsigned)(v >> 32);
  const unsigned nlo = (unsigned)__builtin_amdgcn_update_dpp(lo, lo, CTRL, 0xf, 0xf, false);
  const unsigned nhi = (unsigned)__builtin_amdgcn_update_dpp(hi, hi, CTRL, 0xf, 0xf, false);
  const unsigned long long nv = ((unsigned long long)nhi << 32) | nlo;
  return (nv > v) ? nv : v;
}

__device__ __forceinline__ unsigned long long wave_max_u64(unsigned long long v) {
  v = dpp_max_step<0x111>(v);   // row_shr:1
  v = dpp_max_step<0x112>(v);   // row_shr:2
  v = dpp_max_step<0x114>(v);   // row_shr:4
  v = dpp_max_step<0x118>(v);   // row_shr:8
  v = dpp_max_step<0x142>(v);   // row_bcast:15
  v = dpp_max_step<0x143>(v);   // row_bcast:31
  return v;                      // lane 63 holds the wave max
}

__device__ __forceinline__ unsigned long long bcast63(unsigned long long v) {
  const unsigned lo = (unsigned)__builtin_amdgcn_readlane((int)(unsigned)(v & 0xffffffffull), 63);
  const unsigned hi = (unsigned)__builtin_amdgcn_readlane((int)(unsigned)(v >> 32), 63);
  return ((unsigned long long)hi << 32) | lo;
}

// wave64 inclusive prefix-sum (gfx9 DPP idiom; correctness-verified R9)
__device__ __forceinline__ unsigned wave_iscan_add(unsigned x) {
  x += (unsigned)__builtin_amdgcn_update_dpp(0, (int)x, 0x111, 0xf, 0xf, true); // shr1
  x += (unsigned)__builtin_amdgcn_update_dpp(0, (int)x, 0x112, 0xf, 0xf, true); // shr2
  x += (unsigned)__builtin_amdgcn_update_dpp(0, (int)x, 0x114, 0xf, 0xf, true); // shr4
  x += (unsigned)__builtin_amdgcn_update_dpp(0, (int)x, 0x118, 0xf, 0xf, true); // shr8
  x += (unsigned)__builtin_amdgcn_update_dpp(0, (int)x, 0x142, 0xa, 0xf, true); // bcast15
  x += (unsigned)__builtin_amdgcn_update_dpp(0, (int)x, 0x143, 0xc, 0xf, true); // bcast31
  return x;
}

__device__ __forceinline__ unsigned long long u64max(unsigned long long a,
                                                    unsigned long long b) {
  return (b > a) ? b : a;
}

__device__ __forceinline__ void set_wave_prio_hi() {
#if __has_builtin(__builtin_amdgcn_s_setprio)
  __builtin_amdgcn_s_setprio(3);
#endif
}

// ---------------- FPS body (R16 sort/skip + R22 dual-selection) -------------
// key = (d2 << 12) | (4095 - orig_j)  =>  max key == (max d2, tie -> min j).
// LDS: sPosI[N] | sfi[NOUT] (scatter scratch during init) | sKey2[2][8]
// (ulonglong2: wave top-2 keys; u32-scan scratch during init) | sPosW[2][16]
// (int4 positions of the published elements) | hist[CELLS].
template<int N, int NOUT, int T>
__device__ __forceinline__ void fps_body(char* sm, const float* __restrict__ pb,
                                         int* __restrict__ fi, int b) {
  constexpr int P = N / T;
  constexpr int NW = T / 64;
  constexpr int CELLS = (N >= 4096) ? 512 : 256;
  constexpr int CZB = (CELLS == 512) ? 3 : 2;      // cz bits; x-major slabs
  constexpr int CH = NOUT;                          // scatter chunk (ints)
  constexpr int NCHUNK = N / CH;
  static_assert(CH % P == 0 && N % CH == 0, "chunking");
  static_assert(NW == 8, "dual-selection protocol sized for 8 waves");
  int4* sPosI = (int4*)sm;                                   // [N]
  int*  sfi   = (int*)(sm + (size_t)N * 16);                 // [NOUT]
  unsigned long long* sKey2 =
      (unsigned long long*)(sm + (size_t)N * 16 + NOUT * 4); // ull2[2][8] 256B
  int4* sPosW = (int4*)(sm + (size_t)N * 16 + NOUT * 4 + 256); // [2][16] 512B
  unsigned* hist = (unsigned*)(sm + (size_t)N * 16 + NOUT * 4 + 768); // [CELLS]
  int* sOrd = sfi;   // init-phase alias
  const int tid = threadIdx.x, wid = tid >> 6, lane = tid & 63;
  set_wave_prio_hi();    // protect the serial chain from co-resident waves

  // ---- load positions (original order) ----
  for (int t = tid; t < N; t += T) {
    sPosI[t] = make_int4((int)(pb[3*t]   * 8388608.f),   // exact: 2^-23 multiples
                         (int)(pb[3*t+1] * 8388608.f),
                         (int)(pb[3*t+2] * 8388608.f), 0);
  }
  for (int c = tid; c < CELLS; c += T) hist[c] = 0u;
  __syncthreads();

  // ---- cell histogram (coords are non-negative ints < 2^23) ----
  unsigned myc[P];
#pragma unroll
  for (int r = 0; r < P; r++) {
    const int t = tid + r * T;
    const int4 p4 = sPosI[t];
    const unsigned cell = (((unsigned)p4.x >> 20) << (3 + CZB)) |
                          (((unsigned)p4.y >> 20) << CZB) |
                          ((unsigned)p4.z >> (23 - CZB));
    myc[r] = cell;
    atomicAdd(&hist[cell], 1u);
  }
  __syncthreads();

  // ---- exclusive prefix over hist (CELLS <= T; sKey2 reused as partials) --
  {
    unsigned* sPart = (unsigned*)sKey2;
    unsigned v = (tid < CELLS) ? hist[tid] : 0u;
    const unsigned isc = wave_iscan_add(v);
    if (lane == 63) sPart[wid] = isc;
    __syncthreads();
    unsigned offs = 0;
#pragma unroll
    for (int w2 = 0; w2 < NW; w2++) offs += (w2 < wid) ? sPart[w2] : 0u;
    if (tid < CELLS) hist[tid] = offs + isc - v;   // exclusive cell start
    __syncthreads();
  }

  // ---- slot assignment (destructive atomic on prefix; run-stable slots) ---
  int myslot[P];
#pragma unroll
  for (int r = 0; r < P; r++) myslot[r] = (int)atomicAdd(&hist[myc[r]], 1u);

  // ---- chunked order scatter through sfi + element load -------------------
  int ex[P], ey[P], ez[P]; unsigned einv[P];
  for (int pc = 0; pc < NCHUNK; pc++) {
    __syncthreads();   // sOrd region free (covers slot-assign on first pass)
#pragma unroll
    for (int r = 0; r < P; r++) {
      const int s = myslot[r];
      if (s >= pc * CH && s < (pc + 1) * CH) sOrd[s - pc * CH] = tid + r * T;
    }
    __syncthreads();
    if ((tid * P) / CH == pc) {
#pragma unroll
      for (int e = 0; e < P; e++) {
        const int o = sOrd[tid * P + e - pc * CH];
        const int4 p4 = sPosI[o];
        ex[e] = p4.x; ey[e] = p4.y; ez[e] = p4.z;
        einv[e] = (unsigned)(4095 - o);
      }
    }
  }
  __syncthreads();     // sfi becomes sfi again; sKey2 scratch dead

  // ---- per-thread bbox (tight) ----
  int lox = ex[0], hix = ex[0], loy = ey[0], hiy = ey[0], loz = ez[0], hiz = ez[0];
#pragma unroll
  for (int e = 1; e < P; e++) {
    lox = min(lox, ex[e]); hix = max(hix, ex[e]);
    loy = min(loy, ey[e]); hiy = max(hiy, ey[e]);
    loz = min(loz, ez[e]); hiz = max(hiz, ez[e]);
  }

  // ---- init mind vs point orig-0; per-thread top-1 (bv) and top-2 (t2loc) -
  const int4 p0 = sPosI[0];
  unsigned long long mind[P];
  unsigned long long bv, t2loc;
  {
    unsigned long long tv[P];
#pragma unroll
    for (int e = 0; e < P; e++) {
      const long long dx = ex[e] - p0.x, dy = ey[e] - p0.y, dz = ez[e] - p0.z;
      const unsigned long long d2 =
          (unsigned long long)(dx * dx + dy * dy + dz * dz);   // exact, < 2^48
      const unsigned long long k = (d2 << 12) | einv[e];
      mind[e] = k; tv[e] = k;
    }
#pragma unroll
    for (int s = 1; s < P; s <<= 1)
#pragma unroll
      for (int e = 0; e + s < P; e += 2 * s)
        if (tv[e + s] > tv[e]) tv[e] = tv[e + s];
    bv = tv[0];
    unsigned long long t2 = 0;
#pragma unroll
    for (int e = 0; e < P; e++) t2 = (mind[e] == bv) ? t2 : u64max(t2, mind[e]);
    t2loc = t2;
  }
  if (tid == 0) sfi[0] = 0;

  // ---- serial selection loop (1 or 2 selections per sync round) -----------
  int t = 1, rnd = 0;
  while (t < NOUT) {
    const int pp = rnd & 1; rnd++;              // parity by ROUND (not t!)
    // wave top-1
    unsigned long long v = wave_max_u64(bv);
    const unsigned long long s1 = bcast63(v);
    // wave top-2: top thread contributes its 2nd-best instead
    unsigned long long v2 = wave_max_u64((bv == s1) ? t2loc : bv);
    const unsigned long long s2 = bcast63(v2);
    if (lane == 63) {
      ulonglong2 kv; kv.x = v; kv.y = v2;
      ((ulonglong2*)sKey2)[pp * 8 + wid] = kv;
    }
    // publish positions of the two wave candidates (keys unique -> exactly
    // one element matches each; masked per-lane writes)
#pragma unroll
    for (int e = 0; e < P; e++) {
      if (mind[e] == s1) sPosW[pp * 16 + wid * 2 + 0] = make_int4(ex[e], ey[e], ez[e], 0);
      if (mind[e] == s2) sPosW[pp * 16 + wid * 2 + 1] = make_int4(ex[e], ey[e], ez[e], 0);
    }
    __syncthreads();
    // global top-2 (exact): K1 = max of wave tops; K2 = max of the rest
    ulonglong2 kw[8];
    {
      const ulonglong2* kk = ((const ulonglong2*)sKey2) + pp * 8;
#pragma unroll
      for (int w2 = 0; w2 < 8; w2++) kw[w2] = kk[w2];
    }
    const unsigned long long K1 =
        u64max(u64max(u64max(kw[0].x, kw[1].x), u64max(kw[2].x, kw[3].x)),
               u64max(u64max(kw[4].x, kw[5].x), u64max(kw[6].x, kw[7].x)));
    unsigned long long c[8];
#pragma unroll
    for (int w2 = 0; w2 < 8; w2++) c[w2] = (kw[w2].x == K1) ? kw[w2].y : kw[w2].x;
    const unsigned long long K2 =
        u64max(u64max(u64max(c[0], c[1]), u64max(c[2], c[3])),
               u64max(u64max(c[4], c[5]), u64max(c[6], c[7])));
    // mailbox slots of K1/K2 (published keys are distinct element minds)
    int sA = 0, sB = 0;
#pragma unroll
    for (int w2 = 0; w2 < 8; w2++) {
      if (kw[w2].x == K1) sA = w2 * 2;
      if (kw[w2].x == K2) sB = w2 * 2;
      if (kw[w2].y == K2) sB = w2 * 2 + 1;
    }
    const int4 A  = sPosW[pp * 16 + sA];    // winner position (broadcast read)
    const int4 Bq = sPosW[pp * 16 + sB];    // runner-up position
    // EXACT speculation check: minds only decrease; all non-K1 minds <= K2;
    // if d2(K2elem, w1) >= d2(K2) then K2's mind is unchanged -> next argmax
    // is provably K2.
    const long long dabx = A.x - Bq.x, daby = A.y - Bq.y, dabz = A.z - Bq.z;
    const unsigned long long d2ab =
        (unsigned long long)(dabx * dabx + daby * daby + dabz * dabz);
    const bool canDual = (t + 1 < NOUT) && (d2ab >= (K2 >> 12));
    if (tid == 0) {
      sfi[t] = 4095 - (int)(K1 & 0xFFFull);
      if (canDual) sfi[t + 1] = 4095 - (int)(K2 & 0xFFFull);
    }
    // updates (bbox skip per center; thr = pre-round thread max, valid bound
    // for both since minds only decrease)
    const unsigned long long thr = bv >> 12;
    bool updA, updB = false;
    {
      const int ax = max(max(lox - A.x, A.x - hix), 0);
      const int ay = max(max(loy - A.y, A.y - hiy), 0);
      const int az = max(max(loz - A.z, A.z - hiz), 0);
      const unsigned long long lb =
          (unsigned long long)ax * (unsigned long long)ax +
          (unsigned long long)ay * (unsigned long long)ay +
          (unsigned long long)az * (unsigned long long)az;
      updA = lb < thr;
      if (updA) {
#pragma unroll
        for (int e = 0; e < P; e++) {
          const long long dx = ex[e] - A.x, dy = ey[e] - A.y, dz = ez[e] - A.z;
          const unsigned long long nk =
              ((unsigned long long)(dx * dx + dy * dy + dz * dz) << 12) | einv[e];
          if (nk < mind[e]) mind[e] = nk;
        }
      }
    }
    if (canDual) {
      const int ax = max(max(lox - Bq.x, Bq.x - hix), 0);
      const int ay = max(max(loy - Bq.y, Bq.y - hiy), 0);
      const int az = max(max(loz - Bq.z, Bq.z - hiz), 0);
      const unsigned long long lb =
          (unsigned long long)ax * (unsigned long long)ax +
          (unsigned long long)ay * (unsigned long long)ay +
          (unsigned long long)az * (unsigned long long)az;
      updB = lb < thr;
      if (updB) {
#pragma unroll
        for (int e = 0; e < P; e++) {
          const long long dx = ex[e] - Bq.x, dy = ey[e] - Bq.y, dz = ez[e] - Bq.z;
          const unsigned long long nk =
              ((unsigned long long)(dx * dx + dy * dy + dz * dz) << 12) | einv[e];
          if (nk < mind[e]) mind[e] = nk;
        }
      }
    }
    if (updA || updB) {   // recompute thread top-1/top-2
      unsigned long long tv[P];
#pragma unroll
      for (int e = 0; e < P; e++) tv[e] = mind[e];
#pragma unroll
      for (int s = 1; s < P; s <<= 1)
#pragma unroll
        for (int e = 0; e + s < P; e += 2 * s)
          if (tv[e + s] > tv[e]) tv[e] = tv[e + s];
      bv = tv[0];
      unsigned long long t2 = 0;
#pragma unroll
      for (int e = 0; e < P; e++) t2 = (mind[e] == bv) ? t2 : u64max(t2, mind[e]);
      t2loc = t2;
    }
    t += canDual ? 2 : 1;   // uniform across block (derived from shared data)
  }
  __syncthreads();
  for (int t2 = tid; t2 < NOUT; t2 += T) fi[(size_t)b * NOUT + t2] = sfi[t2];
}

// ---------------- knn (exact f64 top-32, LDS d2s) + conv fused per row ------
// R20: sRed aliased onto the h1s base (h1s and sW2T dead after conv loop).
template<int N, int H, int C, bool HASX, bool FOLDMAX, int T>
__device__ __forceinline__ void knnconv_body(
    char* sm, const float* __restrict__ pb, int b, int i,
    const float* __restrict__ U, const float* __restrict__ Wrel,
    const float* __restrict__ b1, const float* __restrict__ W2,
    const float* __restrict__ b2, float* __restrict__ out, double rr) {
  constexpr int HCHUNK = (C == 64) ? 64 : (C == 128 ? 32 : 16);
  constexpr int STR = HCHUNK + 4;
  constexpr int NW = T / 64;        // k-groups
  constexpr int EPK = 32 / NW;      // k's per thread
  constexpr int BPT = 2048 / T;     // histogram bins per thread
  constexpr int KNNFRONT = N * 8 + 13312;
  constexpr int CONVFRONT = 32 * H * 4 + C * STR * 4;   // sRed aliased in h1s
  constexpr int FRONT = (KNNFRONT > CONVFRONT) ? KNNFRONT : CONVFRONT;
  static_assert(32 * H * 4 >= NW * C * 4, "sRed must fit inside h1s");
  // knn views
  double*   d2s     = (double*)sm;                        // [N]
  unsigned* hist    = (unsigned*)(sm + N * 8);            // [2048]
  int*      candIdx = (int*)(sm + N * 8 + 8192);          // [CAND]
  unsigned* sWT     = (unsigned*)(sm + N * 8 + 12288);    // [NW]
  // conv views (alias the knn front; born after ranking completes)
  float* h1s  = (float*)sm;                               // [32*H]
  float* sW2T = (float*)(sm + 32 * H * 4);                // [C*STR]
  float* sRed = (float*)sm;                               // [NW][C] (aliases h1s)
  // tail (never aliased)
  int*   snbr = (int*)(sm + FRONT);                       // [32]
  float* rel  = (float*)(sm + FRONT + 128);               // [32][3]
  int*   pcnt = (int*)(sm + FRONT + 128 + 384);
  int*   pbin = pcnt + 1;
  const int tid = threadIdx.x;

  // --- distance pass: exact f64 d2 into LDS ---
  const double xi = pb[3*i], yi = pb[3*i+1], zi = pb[3*i+2];
  const double si = (xi*xi + yi*yi) + zi*zi;
  for (int t = tid; t < 2048; t += T) hist[t] = 0u;
  if (tid == 0) *pcnt = 0;
  __syncthreads();
  for (int j = tid; j < N; j += T) {
    double xj = pb[3*j], yj = pb[3*j+1], zj = pb[3*j+2];
    double sj = (xj*xj + yj*yj) + zj*zj;
    double dt = (xi*xj + yi*yj) + zi*zj;
    double d2 = (si + sj) - 2.0*dt;       // exact in f64
    if (j == i) d2 += 1e9;                // self-exclusion
    d2s[j] = d2;
    atomicAdd(&hist[obits((float)d2) >> 21], 1u);
  }
  __syncthreads();
  // --- bin threshold via DPP scan ---
  unsigned lsum = 0;
  const int base = tid * BPT;
#pragma unroll
  for (int q = 0; q < BPT; q++) lsum += hist[base + q];
  const unsigned isc = wave_iscan_add(lsum);
  if ((tid & 63) == 63) sWT[tid >> 6] = isc;
  __syncthreads();
  {
    const int wid = tid >> 6;
    unsigned offs = 0;
#pragma unroll
    for (int w2 = 0; w2 < NW; w2++) offs += (w2 < wid) ? sWT[w2] : 0u;
    const unsigned incl = isc + offs, excl = incl - lsum;
    if (excl < 32u && incl >= 32u) {
      unsigned c = excl;
      for (int q = 0; q < BPT; q++) {
        c += hist[base + q];
        if (c >= 32u) { *pbin = base + q; break; }
      }
    }
  }
  __syncthreads();
  const int binT = *pbin;
  for (int j = tid; j < N; j += T) {
    if ((int)(obits((float)d2s[j]) >> 21) <= binT) {
      int p = atomicAdd(pcnt, 1);
      if (p < CAND) candIdx[p] = j;
    }
  }
  __syncthreads();
  const int M = min(*pcnt, CAND);   // true top-32 superset (proxy monotone)
  for (int c = tid; c < M; c += T) {
    const int j = candIdx[c];
    const double d = d2s[j];
    int rank = 0;
    for (int e = 0; e < M; e++) {
      const int j2 = candIdx[e];
      const double de = d2s[j2];
      rank += (de < d || (de == d && j2 < j)) ? 1 : 0;
    }
    if (rank < 32) snbr[rank] = (d <= rr) ? j : -1;
  }
  __syncthreads();                 // knn LDS dead from here; snbr valid

  // --- rel ---
  if (tid < 32) {
    const int j = snbr[tid];
    float rx = 0.f, ry = 0.f, rz = 0.f;
    if (j >= 0) {
      rx = pb[3*j]   - pb[3*i];
      ry = pb[3*j+1] - pb[3*i+1];
      rz = pb[3*j+2] - pb[3*i+2];
    }
    rel[tid*3+0] = rx; rel[tid*3+1] = ry; rel[tid*3+2] = rz;
  }
  __syncthreads();

  // --- conv phase B: h1[k][h0..h0+3] = relu(U[j] (+b1) + rel . Wrel) ---
  constexpr int QPK = H / 4;
  for (int qi = tid; qi < 32 * QPK; qi += T) {
    const int k = qi / QPK, h0 = (qi - k * QPK) * 4;
    const int j = snbr[k];
    float4 v = make_float4(0.f, 0.f, 0.f, 0.f);
    if (j >= 0) {
      float4 a = HASX ? *(const float4*)&U[((size_t)b * N + j) * H + h0]
                      : *(const float4*)&b1[h0];
      const float rx = rel[k*3], ry = rel[k*3+1], rz = rel[k*3+2];
      const float4 w0 = *(const float4*)&Wrel[h0];
      const float4 w1 = *(const float4*)&Wrel[H + h0];
      const float4 w2 = *(const float4*)&Wrel[2 * H + h0];
      a.x += rx * w0.x + ry * w1.x + rz * w2.x;
      a.y += rx * w0.y + ry * w1.y + rz * w2.y;
      a.z += rx * w0.z + ry * w1.z + rz * w2.z;
      a.w += rx * w0.w + ry * w1.w + rz * w2.w;
      v = make_float4(fmaxf(a.x, 0.f), fmaxf(a.y, 0.f),
                      fmaxf(a.z, 0.f), fmaxf(a.w, 0.f));
    }
    *(float4*)&h1s[k * H + h0] = v;
  }
  const int cc = tid & 63;
  const int kk = tid >> 6;          // 0..NW-1
  constexpr int CC = C / 64;
  float acc[EPK][CC];
#pragma unroll
  for (int e = 0; e < EPK; e++)
#pragma unroll
    for (int q = 0; q < CC; q++) acc[e][q] = 0.f;
  // --- conv phase C: h2 = h1 @ W2 (W2 staged transposed+padded) ---
  for (int hc = 0; hc < H; hc += HCHUNK) {
    __syncthreads();
    for (int idx = tid; idx < HCHUNK * C; idx += T) {
      const int hh = idx / C, c = idx - hh * C;
      sW2T[c * STR + hh] = W2[(size_t)(hc + hh) * C + c];
    }
    __syncthreads();
    for (int hh0 = 0; hh0 < HCHUNK; hh0 += 4) {
      float4 wv[CC];
#pragma unroll
      for (int q = 0; q < CC; q++)
        wv[q] = *(const float4*)&sW2T[(cc + q * 64) * STR + hh0];
#pragma unroll
      for (int e = 0; e < EPK; e++) {
        const float4 hv = *(const float4*)&h1s[(kk + e * NW) * H + hc + hh0];
#pragma unroll
        for (int q = 0; q < CC; q++) {
          acc[e][q] += hv.x * wv[q].x;
          acc[e][q] += hv.y * wv[q].y;
          acc[e][q] += hv.z * wv[q].z;
          acc[e][q] += hv.w * wv[q].w;
        }
      }
    }
  }
  // --- masked max over k, +b2, relu ---
  float m[CC];
#pragma unroll
  for (int q = 0; q < CC; q++) m[q] = -1e9f;
#pragma unroll
  for (int e = 0; e < EPK; e++) {
    if (snbr[kk + e * NW] >= 0) {
#pragma unroll
      for (int q = 0; q < CC; q++) m[q] = fmaxf(m[q], acc[e][q]);
    }
  }
  __syncthreads();   // all conv reads of h1s done before sRed overwrites it
#pragma unroll
  for (int q = 0; q < CC; q++) sRed[kk * C + cc + q * 64] = m[q];
  __syncthreads();
  if (kk == 0) {
#pragma unroll
    for (int q = 0; q < CC; q++) {
      const int c = cc + q * 64;
      float mm = sRed[c];
#pragma unroll
      for (int w2 = 1; w2 < NW; w2++) mm = fmaxf(mm, sRed[w2 * C + c]);
      const float o = (mm > -5e8f) ? (mm + b2[c]) : -1e9f;
      const float r = fmaxf(o, 0.f);
      if (FOLDMAX) {
        atomicMax((int*)&out[b * C + c], __float_as_int(r));  // r >= 0
      } else {
        out[((size_t)b * N + i) * C + c] = r;
      }
    }
  }
}

// ---------------- stage kernels (distinct names for profiling) --------------
template<int N, int NOUT, int H, int C, bool HASX, int SMSIZE>
__device__ __forceinline__ void stage_fused_impl(
    const float* pos, double rr, int* fi, const float* U, const float* Wrel,
    const float* b1, const float* W2, const float* b2, float* out, char* sm) {
  if (blockIdx.x < NB) {
    fps_body<N, NOUT, 512>(sm, pos + (size_t)blockIdx.x * N * 3, fi, blockIdx.x);
  } else {
    const int row = blockIdx.x - NB;
    const int b = row / N;
    const int i = row - b * N;
    knnconv_body<N, H, C, HASX, false, 512>(sm, pos + (size_t)b * N * 3, b, i,
                                            U, Wrel, b1, W2, b2, out, rr);
  }
}

__global__ __launch_bounds__(512, 2)
void stage1_kernel(const float* __restrict__ pos, double rr, int* __restrict__ fi,
                   const float* __restrict__ Wrel, const float* __restrict__ b1,
                   const float* __restrict__ W2, const float* __restrict__ b2,
                   float* __restrict__ out) {
  // fps1 footprint = 65536 + 8192 + 256 (sKey2) + 512 (sPosW) + 2048 (hist)
  // = 76544; 2x = 153.1KB <= 160KB -> 2 blk/CU.
  __shared__ __align__(16) char sm[76544];
  stage_fused_impl<4096, 2048, 64, 64, false, 76544>(
      pos, rr, fi, nullptr, Wrel, b1, W2, b2, out, sm);
}

__global__ __launch_bounds__(512, 2)
void stage2_kernel(const float* __restrict__ pos, double rr, int* __restrict__ fi,
                   const float* __restrict__ U, const float* __restrict__ Wrel,
                   const float* __restrict__ b1, const float* __restrict__ W2,
                   const float* __restrict__ b2, float* __restrict__ out) {
  // fps2 footprint = 32768 + 2048 + 256 + 512 + 1024 = 36608 <= 39440.
  __shared__ __align__(16) char sm[39440];
  stage_fused_impl<2048, 512, 128, 128, true, 39440>(
      pos, rr, fi, U, Wrel, b1, W2, b2, out, sm);
}

__global__ __launch_bounds__(512)
void stage3_kernel(const float* __restrict__ pos, double rr,
                   const float* __restrict__ U, const float* __restrict__ Wrel,
                   const float* __restrict__ b1, const float* __restrict__ W2,
                   const float* __restrict__ b2, float* __restrict__ feat) {
  // CONVFRONT = 32*256*4 + 256*20*4 = 53248 (sRed aliased); + tail -> 53776.
  __shared__ __align__(16) char sm[53776];
  const int b = blockIdx.x / 512;
  const int i = blockIdx.x - b * 512;
  knnconv_body<512, 256, 256, true, true, 512>(sm, pos + (size_t)b * 512 * 3,
                                               b, i, U, Wrel, b1, W2, b2,
                                               feat, rr);
}

// ---------------- fused gather + preproj (U = x[fi] @ W[:CIN] + b) ----------
template<int CIN, int HH>
__global__ __launch_bounds__(HH)
void gp_kernel(const float* __restrict__ X, const float* __restrict__ posPrev,
               const int* __restrict__ fi, int Nprev, int M,
               const float* __restrict__ W, const float* __restrict__ bias,
               float* __restrict__ U, float* __restrict__ posDst) {
  const int row = blockIdx.x;
  const int b = row / M;
  const int tid = threadIdx.x;
  const int j = fi[row];
  __shared__ float sx[CIN];
  if (tid < CIN) sx[tid] = X[((size_t)b * Nprev + j) * CIN + tid];
  if (tid < 3) posDst[(size_t)row * 3 + tid] = posPrev[((size_t)b * Nprev + j) * 3 + tid];
  __syncthreads();
  float a = bias[tid];
  for (int f = 0; f < CIN; f++) a = fmaf(sx[f], W[f * HH + tid], a);
  U[(size_t)row * HH + tid] = a;
}

// ---------------- classifier/defense heads (feat precomputed) ---------------
__global__ __launch_bounds__(256) void head_kernel(
    const float* __restrict__ feat,
    const float* __restrict__ Wc1, const float* __restrict__ bc1,
    const float* __restrict__ Wc2, const float* __restrict__ bc2,
    const float* __restrict__ Wc3, const float* __restrict__ bc3,
    const float* __restrict__ Wd1, const float* __restrict__ bd1,
    const float* __restrict__ Wd2, const float* __restrict__ bd2,
    float* __restrict__ out) {
  const int b = blockIdx.x, tid = threadIdx.x;
  __shared__ float sf[256], sh[256], sh2[256], shd[256], sl[48];
  sf[tid] = feat[b * 256 + tid];
  __syncthreads();
  float a = bc1[tid], ad = bd1[tid];
  for (int f = 0; f < 256; f++) {
    const float fv = sf[f];
    a  = fmaf(fv, Wc1[f * 256 + tid], a);
    ad = fmaf(fv, Wd1[f * 256 + tid], ad);
  }
  sh[tid] = fmaxf(a, 0.f);
  shd[tid] = fmaxf(ad, 0.f);
  __syncthreads();
  float a2 = bc2[tid];
  for (int f = 0; f < 256; f++) a2 = fmaf(sh[f], Wc2[f * 256 + tid], a2);
  sh2[tid] = fmaxf(a2, 0.f);
  __syncthreads();
  if (tid < 40) {
    float l = bc3[tid];
    for (int f = 0; f < 256; f++) l = fmaf(sh2[f], Wc3[f * 40 + tid], l);
    sl[tid] = l;
  }
  if (tid >= 64 && tid < 66) {
    const int q = tid - 64;
    float l = bd2[q];
    for (int f = 0; f < 256; f++) l = fmaf(shd[f], Wd2[f * 2 + q], l);
    sl[40 + q] = l;
  }
  __syncthreads();
  if (tid == 0) {
    float m0 = sl[0];
    for (int q = 1; q < 40; q++) m0 = fmaxf(m0, sl[q]);
    float s = 0.f;
    for (int q = 0; q < 40; q++) s += expf(sl[q] - m0);
    const float ls = logf(s);
    for (int q = 0; q < 40; q++) out[b * 40 + q] = sl[q] - m0 - ls;
    const float m1 = fmaxf(sl[40], sl[41]);
    const float s1 = expf(sl[40] - m1) + expf(sl[41] - m1);
    const float ls1 = logf(s1);
    out[320 + b * 2 + 0] = sl[40] - m1 - ls1;
    out[320 + b * 2 + 1] = sl[41] - m1 - ls1;
  }
}

// ---------------------------------------------------------------------------
extern "C" void kernel_launch(void* const* d_in, const int* in_sizes, int n_in,
                              void* d_out, int out_size, void* d_ws, size_t ws_size,
                              hipStream_t stream) {
  (void)in_sizes; (void)n_in; (void)out_size; (void)ws_size;
  const float* pos = (const float*)d_in[0];
  const float* W1a = (const float*)d_in[1];  const float* b1a = (const float*)d_in[2];
  const float* W1b = (const float*)d_in[3];  const float* b1b = (const float*)d_in[4];
  const float* W2a = (const float*)d_in[5];  const float* b2a = (const float*)d_in[6];
  const float* W2b = (const float*)d_in[7];  const float* b2b = (const float*)d_in[8];
  const float* W3a = (const float*)d_in[9];  const float* b3a = (const float*)d_in[10];
  const float* W3b = (const float*)d_in[11]; const float* b3b = (const float*)d_in[12];
  const float* Wc1 = (const float*)d_in[13]; const float* bc1 = (const float*)d_in[14];
  const float* Wc2 = (const float*)d_in[15]; const float* bc2 = (const float*)d_in[16];
  const float* Wc3 = (const float*)d_in[17]; const float* bc3 = (const float*)d_in[18];
  const float* Wd1 = (const float*)d_in[19]; const float* bd1 = (const float*)d_in[20];
  const float* Wd2 = (const float*)d_in[21]; const float* bd2 = (const float*)d_in[22];
  float* out = (float*)d_out;

  char* w = (char*)d_ws;
  auto alloc = [&](size_t bytes) -> void* {
    void* p = (void*)w;
    w += (bytes + 255) & ~(size_t)255;
    return p;
  };
  int*   fi1  = (int*)  alloc((size_t)NB*2048*4);
  float* x1   = (float*)alloc((size_t)NB*4096*64*4);
  float* pos2 = (float*)alloc((size_t)NB*2048*3*4);
  float* U2   = (float*)alloc((size_t)NB*2048*128*4);
  float* x2   = (float*)alloc((size_t)NB*2048*128*4);
  int*   fi2  = (int*)  alloc((size_t)NB*512*4);
  float* pos3 = (float*)alloc((size_t)NB*512*3*4);
  float* U3   = (float*)alloc((size_t)NB*512*256*4);
  float* feat = (float*)alloc((size_t)NB*256*4);

  // feat = 0 (atomicMax target; all pooled values are >= 0 post-relu)
  hipMemsetAsync(feat, 0, (size_t)NB * 256 * 4, stream);

  // stage 1: {fps1 || knn1+conv1}  (both depend only on pos)
  stage1_kernel<<<NB + NB * 4096, 512, 0, stream>>>(
      pos, 0.2 * 0.2, fi1, W1a, b1a, W1b, b1b, x1);

  // gather1 + preproj2 (U2 = x1[fi1] @ W2a[:64] + b2a)
  gp_kernel<64, 128><<<NB * 2048, 128, 0, stream>>>(
      x1, pos, fi1, 4096, 2048, W2a, b2a, U2, pos2);

  // stage 2: {fps2 || knn2+conv2}
  stage2_kernel<<<NB + NB * 2048, 512, 0, stream>>>(
      pos2, 0.4 * 0.4, fi2, U2, W2a + (size_t)64 * 128, b2a, W2b, b2b, x2);

  // gather2 + preproj3
  gp_kernel<128, 256><<<NB * 512, 256, 0, stream>>>(
      x2, pos2, fi2, 2048, 512, W3a, b3a, U3, pos3);

  // stage 3: knn3+conv3 with fused global max-pool (atomicMax into feat)
  stage3_kernel<<<NB * 512, 512, 0, stream>>>(
      pos3, 1.0, U3, W3a + (size_t)128 * 256, b3a, W3b, b3b, feat);

  // heads
  head_kernel<<<NB, 256, 0, stream>>>(feat, Wc1, bc1, Wc2, bc2, Wc3, bc3,
                                      Wd1, bd1, Wd2, bd2, out);
}

// Round 10
// 2359.965 us; speedup vs baseline: 1.4651x; 1.4651x over previous
//
#include <hip/hip_runtime.h>

// ---------------------------------------------------------------------------
// PointNet++ (defense variant) forward on MI355X.
// B=8, N=4096 -> 2048 -> 512, K=32 neighbors. Geometry is EXACT: positions are
// multiples of 2^-23 (f64 knn d2 / i64 fps d2 are exact) — discrete choices
// match an np-f64 reference exactly.
// R16: cell-sort + per-thread bbox wave-skip: stage1 1578 -> 1363us (BEST).
// R17 column-skip 1671 / R19 paired-batch 3582 / R21 mailbox 2022 /
// R22 dual-selection 2405: ALL REGRESSED -> reverted. Conclusion: at real
// clocks (~1.5-1.8GHz under latency-bound load) the measured 666ns/iter
// MATCHES the critical-path sum (pos-read+update+rereduce+DPP+publish+
// barrier+partial-read+tree) — the R16 loop is at its structural floor;
// every added mechanism costs more issue/latency than it removes.
// R20: stage3 sRed-in-h1s alias (3 blk/CU): null, harmless, kept.
// R23: R20-exact restore + ONE isolated micro-change: partial reads as
// 4x b128 (ulonglong2) instead of 8 scalar u64 (R18 bundled this with
// Morton; testing it alone — fewer dependent LDS issues, merged latency).
// ---------------------------------------------------------------------------

#define NB 8

__device__ __forceinline__ unsigned obits(float f) {
  unsigned u = __float_as_uint(f);
  return (u & 0x80000000u) ? ~u : (u | 0x80000000u);
}

static constexpr int CAND = 1024;

// ---------------- DPP helpers (VALU cross-lane, no LDS pipe) ----------------
template<int CTRL>
__device__ __forceinline__ unsigned long long dpp_max_step(unsigned long long v) {
  const int lo = (int)(unsigned)(v & 0xffffffffull);
  const int hi = (int)(unsigned)(v >> 32);
  const unsigned nlo = (unsigned)__builtin_amdgcn_update_dpp(lo, lo, CTRL, 0xf, 0xf, false);
  const unsigned nhi = (unsigned)__builtin_amdgcn_update_dpp(hi, hi, CTRL, 0xf, 0xf, false);
  const unsigned long long nv = ((unsigned long long)nhi << 32) | nlo;
  return (nv > v) ? nv : v;
}

// wave64 inclusive prefix-sum (gfx9 DPP idiom; correctness-verified R9)
__device__ __forceinline__ unsigned wave_iscan_add(unsigned x) {
  x += (unsigned)__builtin_amdgcn_update_dpp(0, (int)x, 0x111, 0xf, 0xf, true); // shr1
  x += (unsigned)__builtin_amdgcn_update_dpp(0, (int)x, 0x112, 0xf, 0xf, true); // shr2
  x += (unsigned)__builtin_amdgcn_update_dpp(0, (int)x, 0x114, 0xf, 0xf, true); // shr4
  x += (unsigned)__builtin_amdgcn_update_dpp(0, (int)x, 0x118, 0xf, 0xf, true); // shr8
  x += (unsigned)__builtin_amdgcn_update_dpp(0, (int)x, 0x142, 0xa, 0xf, true); // bcast15
  x += (unsigned)__builtin_amdgcn_update_dpp(0, (int)x, 0x143, 0xc, 0xf, true); // bcast31
  return x;
}

__device__ __forceinline__ unsigned long long u64max(unsigned long long a,
                                                    unsigned long long b) {
  return (b > a) ? b : a;
}

__device__ __forceinline__ void set_wave_prio_hi() {
#if __has_builtin(__builtin_amdgcn_s_setprio)
  __builtin_amdgcn_s_setprio(3);
#endif
}

// ---------------- FPS body (R16-exact: cell-sort + per-thread bbox skip) ----
// key = (d2 << 12) | (4095 - orig_j)  =>  max key == (max d2, tie -> min j).
// LDS layout: sPosI[N] (orig order) | sfi[NOUT] (order-scatter scratch during
// init) | sKey[2][NW] (scan-partial scratch during init) | hist[CELLS].
template<int N, int NOUT, int T>
__device__ __forceinline__ void fps_body(char* sm, const float* __restrict__ pb,
                                         int* __restrict__ fi, int b) {
  constexpr int P = N / T;
  constexpr int NW = T / 64;
  constexpr int CELLS = (N >= 4096) ? 512 : 256;
  constexpr int CZB = (CELLS == 512) ? 3 : 2;      // cz bits; x-major slabs
  constexpr int CH = NOUT;                          // scatter chunk (ints)
  constexpr int NCHUNK = N / CH;
  static_assert(CH % P == 0 && N % CH == 0, "chunking");
  int4* sPosI = (int4*)sm;                                   // [N]
  int*  sfi   = (int*)(sm + (size_t)N * 16);                 // [NOUT]
  unsigned long long* sKey =
      (unsigned long long*)(sm + (size_t)N * 16 + NOUT * 4); // [2][NW]
  unsigned* hist = (unsigned*)(sm + (size_t)N * 16 + NOUT * 4 + 128); // [CELLS]
  int* sOrd = sfi;   // init-phase alias
  const int tid = threadIdx.x, wid = tid >> 6, lane = tid & 63;
  set_wave_prio_hi();    // protect the serial chain from co-resident waves

  // ---- load positions (original order; winner lookups stay orig-indexed) --
  for (int t = tid; t < N; t += T) {
    sPosI[t] = make_int4((int)(pb[3*t]   * 8388608.f),   // exact: 2^-23 multiples
                         (int)(pb[3*t+1] * 8388608.f),
                         (int)(pb[3*t+2] * 8388608.f), 0);
  }
  for (int c = tid; c < CELLS; c += T) hist[c] = 0u;
  __syncthreads();

  // ---- cell histogram (coords are non-negative ints < 2^23) ----
  unsigned myc[P];
#pragma unroll
  for (int r = 0; r < P; r++) {
    const int t = tid + r * T;
    const int4 p4 = sPosI[t];
    const unsigned cell = (((unsigned)p4.x >> 20) << (3 + CZB)) |
                          (((unsigned)p4.y >> 20) << CZB) |
                          ((unsigned)p4.z >> (23 - CZB));
    myc[r] = cell;
    atomicAdd(&hist[cell], 1u);
  }
  __syncthreads();

  // ---- exclusive prefix over hist (CELLS <= T; sKey reused as partials) ---
  {
    unsigned* sPart = (unsigned*)sKey;
    unsigned v = (tid < CELLS) ? hist[tid] : 0u;
    const unsigned isc = wave_iscan_add(v);
    if (lane == 63) sPart[wid] = isc;
    __syncthreads();
    unsigned offs = 0;
#pragma unroll
    for (int w2 = 0; w2 < NW; w2++) offs += (w2 < wid) ? sPart[w2] : 0u;
    if (tid < CELLS) hist[tid] = offs + isc - v;   // exclusive cell start
    __syncthreads();
  }

  // ---- slot assignment (destructive atomic on prefix; run-stable slots) ---
  int myslot[P];
#pragma unroll
  for (int r = 0; r < P; r++) myslot[r] = (int)atomicAdd(&hist[myc[r]], 1u);

  // ---- chunked order scatter through sfi + element load -------------------
  int ex[P], ey[P], ez[P]; unsigned einv[P];
  for (int pc = 0; pc < NCHUNK; pc++) {
    __syncthreads();   // sOrd region free (covers slot-assign on first pass)
#pragma unroll
    for (int r = 0; r < P; r++) {
      const int s = myslot[r];
      if (s >= pc * CH && s < (pc + 1) * CH) sOrd[s - pc * CH] = tid + r * T;
    }
    __syncthreads();
    if ((tid * P) / CH == pc) {
#pragma unroll
      for (int e = 0; e < P; e++) {
        const int o = sOrd[tid * P + e - pc * CH];
        const int4 p4 = sPosI[o];
        ex[e] = p4.x; ey[e] = p4.y; ez[e] = p4.z;
        einv[e] = (unsigned)(4095 - o);
      }
    }
  }
  __syncthreads();     // sfi becomes sfi again

  // ---- per-thread bbox (tight: actual min/max of its P points) ------------
  int lox = ex[0], hix = ex[0], loy = ey[0], hiy = ey[0], loz = ez[0], hiz = ez[0];
#pragma unroll
  for (int e = 1; e < P; e++) {
    lox = min(lox, ex[e]); hix = max(hix, ex[e]);
    loy = min(loy, ey[e]); hiy = max(hiy, ey[e]);
    loz = min(loz, ez[e]); hiz = max(hiz, ez[e]);
  }

  // ---- init mind vs point orig-0 ----
  const int4 p0 = sPosI[0];
  unsigned long long mind[P];
  unsigned long long bv;
  {
    unsigned long long tv[P];
#pragma unroll
    for (int e = 0; e < P; e++) {
      const long long dx = ex[e] - p0.x, dy = ey[e] - p0.y, dz = ez[e] - p0.z;
      const unsigned long long d2 =
          (unsigned long long)(dx * dx + dy * dy + dz * dz);   // exact, < 2^48
      const unsigned long long k = (d2 << 12) | einv[e];
      mind[e] = k; tv[e] = k;
    }
#pragma unroll
    for (int s = 1; s < P; s <<= 1)
#pragma unroll
      for (int e = 0; e + s < P; e += 2 * s)
        if (tv[e + s] > tv[e]) tv[e] = tv[e + s];
    bv = tv[0];
  }
  if (tid == 0) sfi[0] = 0;

  // ---- serial selection loop ----
  for (int t = 1; t < NOUT; t++) {
    unsigned long long v = bv;
    v = dpp_max_step<0x111>(v);   // row_shr:1
    v = dpp_max_step<0x112>(v);   // row_shr:2
    v = dpp_max_step<0x114>(v);   // row_shr:4
    v = dpp_max_step<0x118>(v);   // row_shr:8
    v = dpp_max_step<0x142>(v);   // row_bcast:15
    v = dpp_max_step<0x143>(v);   // row_bcast:31
    const int pp = t & 1;
    if (lane == 63) sKey[pp * NW + wid] = v;
    __syncthreads();   // only barrier per iter; LDS-only (no vmcnt drain)
    unsigned long long best;
    if (NW == 8) {     // R23: 64B contiguous partials -> 4x b128 reads
      const ulonglong2* sK2 = (const ulonglong2*)(sKey + pp * 8);
      const ulonglong2 a0 = sK2[0], a1 = sK2[1], a2 = sK2[2], a3 = sK2[3];
      best = u64max(u64max(u64max(a0.x, a0.y), u64max(a1.x, a1.y)),
                    u64max(u64max(a2.x, a2.y), u64max(a3.x, a3.y)));
    } else {
      unsigned long long k0 = sKey[pp*NW+0];
#pragma unroll
      for (int w2 = 1; w2 < NW; w2++) k0 = u64max(k0, sKey[pp*NW+w2]);
      best = k0;
    }
    const int ii = 4095 - (int)(best & 0xFFFull);
    if (tid == 0) sfi[t] = ii;
    const int4 wc = sPosI[ii];    // single b128 same-address broadcast

    // EXACT bbox skip: lb >= max_e mind_d2 (= bv>>12)  =>  no element of this
    // thread can change (nd_e >= lb >= mind_e). Vector branch -> execz skip.
    const int ax = max(max(lox - wc.x, wc.x - hix), 0);
    const int ay = max(max(loy - wc.y, wc.y - hiy), 0);
    const int az = max(max(loz - wc.z, wc.z - hiz), 0);
    const unsigned long long lb =
        (unsigned long long)ax * (unsigned long long)ax +
        (unsigned long long)ay * (unsigned long long)ay +
        (unsigned long long)az * (unsigned long long)az;
    if (lb < (bv >> 12)) {
      unsigned long long tv[P];
#pragma unroll
      for (int e = 0; e < P; e++) {
        const long long dx = ex[e] - wc.x, dy = ey[e] - wc.y, dz = ez[e] - wc.z;
        const unsigned long long nd =
            (unsigned long long)(dx * dx + dy * dy + dz * dz);
        const unsigned long long nk = (nd << 12) | einv[e];
        unsigned long long mk = mind[e];
        mk = (nk < mk) ? nk : mk;
        mind[e] = mk;
        tv[e] = mk;
      }
#pragma unroll
      for (int s = 1; s < P; s <<= 1)
#pragma unroll
        for (int e = 0; e + s < P; e += 2 * s)
          if (tv[e + s] > tv[e]) tv[e] = tv[e + s];
      bv = tv[0];
    }
  }
  __syncthreads();
  for (int t = tid; t < NOUT; t += T) fi[(size_t)b * NOUT + t] = sfi[t];
}

// ---------------- knn (exact f64 top-32, LDS d2s) + conv fused per row ------
// R20: sRed aliased onto the h1s base (h1s and sW2T are dead after the conv
// loop; one extra barrier before the sRed write). Needs 32*H >= NW*C.
template<int N, int H, int C, bool HASX, bool FOLDMAX, int T>
__device__ __forceinline__ void knnconv_body(
    char* sm, const float* __restrict__ pb, int b, int i,
    const float* __restrict__ U, const float* __restrict__ Wrel,
    const float* __restrict__ b1, const float* __restrict__ W2,
    const float* __restrict__ b2, float* __restrict__ out, double rr) {
  constexpr int HCHUNK = (C == 64) ? 64 : (C == 128 ? 32 : 16);
  constexpr int STR = HCHUNK + 4;
  constexpr int NW = T / 64;        // k-groups
  constexpr int EPK = 32 / NW;      // k's per thread
  constexpr int BPT = 2048 / T;     // histogram bins per thread
  constexpr int KNNFRONT = N * 8 + 13312;
  constexpr int CONVFRONT = 32 * H * 4 + C * STR * 4;   // sRed aliased in h1s
  constexpr int FRONT = (KNNFRONT > CONVFRONT) ? KNNFRONT : CONVFRONT;
  static_assert(32 * H * 4 >= NW * C * 4, "sRed must fit inside h1s");
  // knn views
  double*   d2s     = (double*)sm;                        // [N]
  unsigned* hist    = (unsigned*)(sm + N * 8);            // [2048]
  int*      candIdx = (int*)(sm + N * 8 + 8192);          // [CAND]
  unsigned* sWT     = (unsigned*)(sm + N * 8 + 12288);    // [NW]
  // conv views (alias the knn front; born after ranking completes)
  float* h1s  = (float*)sm;                               // [32*H]
  float* sW2T = (float*)(sm + 32 * H * 4);                // [C*STR]
  float* sRed = (float*)sm;                               // [NW][C] (aliases h1s)
  // tail (never aliased)
  int*   snbr = (int*)(sm + FRONT);                       // [32]
  float* rel  = (float*)(sm + FRONT + 128);               // [32][3]
  int*   pcnt = (int*)(sm + FRONT + 128 + 384);
  int*   pbin = pcnt + 1;
  const int tid = threadIdx.x;

  // --- distance pass: exact f64 d2 into LDS ---
  const double xi = pb[3*i], yi = pb[3*i+1], zi = pb[3*i+2];
  const double si = (xi*xi + yi*yi) + zi*zi;
  for (int t = tid; t < 2048; t += T) hist[t] = 0u;
  if (tid == 0) *pcnt = 0;
  __syncthreads();
  for (int j = tid; j < N; j += T) {
    double xj = pb[3*j], yj = pb[3*j+1], zj = pb[3*j+2];
    double sj = (xj*xj + yj*yj) + zj*zj;
    double dt = (xi*xj + yi*yj) + zi*zj;
    double d2 = (si + sj) - 2.0*dt;       // exact in f64
    if (j == i) d2 += 1e9;                // self-exclusion
    d2s[j] = d2;
    atomicAdd(&hist[obits((float)d2) >> 21], 1u);
  }
  __syncthreads();
  // --- bin threshold via DPP scan ---
  unsigned lsum = 0;
  const int base = tid * BPT;
#pragma unroll
  for (int q = 0; q < BPT; q++) lsum += hist[base + q];
  const unsigned isc = wave_iscan_add(lsum);
  if ((tid & 63) == 63) sWT[tid >> 6] = isc;
  __syncthreads();
  {
    const int wid = tid >> 6;
    unsigned offs = 0;
#pragma unroll
    for (int w2 = 0; w2 < NW; w2++) offs += (w2 < wid) ? sWT[w2] : 0u;
    const unsigned incl = isc + offs, excl = incl - lsum;
    if (excl < 32u && incl >= 32u) {
      unsigned c = excl;
      for (int q = 0; q < BPT; q++) {
        c += hist[base + q];
        if (c >= 32u) { *pbin = base + q; break; }
      }
    }
  }
  __syncthreads();
  const int binT = *pbin;
  for (int j = tid; j < N; j += T) {
    if ((int)(obits((float)d2s[j]) >> 21) <= binT) {
      int p = atomicAdd(pcnt, 1);
      if (p < CAND) candIdx[p] = j;
    }
  }
  __syncthreads();
  const int M = min(*pcnt, CAND);   // true top-32 superset (proxy monotone)
  for (int c = tid; c < M; c += T) {
    const int j = candIdx[c];
    const double d = d2s[j];
    int rank = 0;
    for (int e = 0; e < M; e++) {
      const int j2 = candIdx[e];
      const double de = d2s[j2];
      rank += (de < d || (de == d && j2 < j)) ? 1 : 0;
    }
    if (rank < 32) snbr[rank] = (d <= rr) ? j : -1;
  }
  __syncthreads();                 // knn LDS dead from here; snbr valid

  // --- rel ---
  if (tid < 32) {
    const int j = snbr[tid];
    float rx = 0.f, ry = 0.f, rz = 0.f;
    if (j >= 0) {
      rx = pb[3*j]   - pb[3*i];
      ry = pb[3*j+1] - pb[3*i+1];
      rz = pb[3*j+2] - pb[3*i+2];
    }
    rel[tid*3+0] = rx; rel[tid*3+1] = ry; rel[tid*3+2] = rz;
  }
  __syncthreads();

  // --- conv phase B: h1[k][h0..h0+3] = relu(U[j] (+b1) + rel . Wrel) ---
  constexpr int QPK = H / 4;
  for (int qi = tid; qi < 32 * QPK; qi += T) {
    const int k = qi / QPK, h0 = (qi - k * QPK) * 4;
    const int j = snbr[k];
    float4 v = make_float4(0.f, 0.f, 0.f, 0.f);
    if (j >= 0) {
      float4 a = HASX ? *(const float4*)&U[((size_t)b * N + j) * H + h0]
                      : *(const float4*)&b1[h0];
      const float rx = rel[k*3], ry = rel[k*3+1], rz = rel[k*3+2];
      const float4 w0 = *(const float4*)&Wrel[h0];
      const float4 w1 = *(const float4*)&Wrel[H + h0];
      const float4 w2 = *(const float4*)&Wrel[2 * H + h0];
      a.x += rx * w0.x + ry * w1.x + rz * w2.x;
      a.y += rx * w0.y + ry * w1.y + rz * w2.y;
      a.z += rx * w0.z + ry * w1.z + rz * w2.z;
      a.w += rx * w0.w + ry * w1.w + rz * w2.w;
      v = make_float4(fmaxf(a.x, 0.f), fmaxf(a.y, 0.f),
                      fmaxf(a.z, 0.f), fmaxf(a.w, 0.f));
    }
    *(float4*)&h1s[k * H + h0] = v;
  }
  const int cc = tid & 63;
  const int kk = tid >> 6;          // 0..NW-1
  constexpr int CC = C / 64;
  float acc[EPK][CC];
#pragma unroll
  for (int e = 0; e < EPK; e++)
#pragma unroll
    for (int q = 0; q < CC; q++) acc[e][q] = 0.f;
  // --- conv phase C: h2 = h1 @ W2 (W2 staged transposed+padded) ---
  for (int hc = 0; hc < H; hc += HCHUNK) {
    __syncthreads();
    for (int idx = tid; idx < HCHUNK * C; idx += T) {
      const int hh = idx / C, c = idx - hh * C;
      sW2T[c * STR + hh] = W2[(size_t)(hc + hh) * C + c];
    }
    __syncthreads();
    for (int hh0 = 0; hh0 < HCHUNK; hh0 += 4) {
      float4 wv[CC];
#pragma unroll
      for (int q = 0; q < CC; q++)
        wv[q] = *(const float4*)&sW2T[(cc + q * 64) * STR + hh0];
#pragma unroll
      for (int e = 0; e < EPK; e++) {
        const float4 hv = *(const float4*)&h1s[(kk + e * NW) * H + hc + hh0];
#pragma unroll
        for (int q = 0; q < CC; q++) {
          acc[e][q] += hv.x * wv[q].x;
          acc[e][q] += hv.y * wv[q].y;
          acc[e][q] += hv.z * wv[q].z;
          acc[e][q] += hv.w * wv[q].w;
        }
      }
    }
  }
  // --- masked max over k, +b2, relu ---
  float m[CC];
#pragma unroll
  for (int q = 0; q < CC; q++) m[q] = -1e9f;
#pragma unroll
  for (int e = 0; e < EPK; e++) {
    if (snbr[kk + e * NW] >= 0) {
#pragma unroll
      for (int q = 0; q < CC; q++) m[q] = fmaxf(m[q], acc[e][q]);
    }
  }
  __syncthreads();   // all conv reads of h1s done before sRed overwrites it
#pragma unroll
  for (int q = 0; q < CC; q++) sRed[kk * C + cc + q * 64] = m[q];
  __syncthreads();
  if (kk == 0) {
#pragma unroll
    for (int q = 0; q < CC; q++) {
      const int c = cc + q * 64;
      float mm = sRed[c];
#pragma unroll
      for (int w2 = 1; w2 < NW; w2++) mm = fmaxf(mm, sRed[w2 * C + c]);
      const float o = (mm > -5e8f) ? (mm + b2[c]) : -1e9f;
      const float r = fmaxf(o, 0.f);
      if (FOLDMAX) {
        atomicMax((int*)&out[b * C + c], __float_as_int(r));  // r >= 0
      } else {
        out[((size_t)b * N + i) * C + c] = r;
      }
    }
  }
}

// ---------------- stage kernels (distinct names for profiling) --------------
template<int N, int NOUT, int H, int C, bool HASX, int SMSIZE>
__device__ __forceinline__ void stage_fused_impl(
    const float* pos, double rr, int* fi, const float* U, const float* Wrel,
    const float* b1, const float* W2, const float* b2, float* out, char* sm) {
  if (blockIdx.x < NB) {
    fps_body<N, NOUT, 512>(sm, pos + (size_t)blockIdx.x * N * 3, fi, blockIdx.x);
  } else {
    const int row = blockIdx.x - NB;
    const int b = row / N;
    const int i = row - b * N;
    knnconv_body<N, H, C, HASX, false, 512>(sm, pos + (size_t)b * N * 3, b, i,
                                            U, Wrel, b1, W2, b2, out, rr);
  }
}

__global__ __launch_bounds__(512, 2)
void stage1_kernel(const float* __restrict__ pos, double rr, int* __restrict__ fi,
                   const float* __restrict__ Wrel, const float* __restrict__ b1,
                   const float* __restrict__ W2, const float* __restrict__ b2,
                   float* __restrict__ out) {
  // fps1 footprint = 65536 + 8192 + 128 + 2048 = 75904;
  // 2x = 151.8KB <= 160KB -> 2 blk/CU.
  __shared__ __align__(16) char sm[75904];
  stage_fused_impl<4096, 2048, 64, 64, false, 75904>(
      pos, rr, fi, nullptr, Wrel, b1, W2, b2, out, sm);
}

__global__ __launch_bounds__(512, 2)
void stage2_kernel(const float* __restrict__ pos, double rr, int* __restrict__ fi,
                   const float* __restrict__ U, const float* __restrict__ Wrel,
                   const float* __restrict__ b1, const float* __restrict__ W2,
                   const float* __restrict__ b2, float* __restrict__ out) {
  // fps2 footprint = 32768 + 2048 + 128 + 1024 = 35968 <= 39440 (knnconv2).
  __shared__ __align__(16) char sm[39440];
  stage_fused_impl<2048, 512, 128, 128, true, 39440>(
      pos, rr, fi, U, Wrel, b1, W2, b2, out, sm);
}

__global__ __launch_bounds__(512)
void stage3_kernel(const float* __restrict__ pos, double rr,
                   const float* __restrict__ U, const float* __restrict__ Wrel,
                   const float* __restrict__ b1, const float* __restrict__ W2,
                   const float* __restrict__ b2, float* __restrict__ feat) {
  // CONVFRONT = 32*256*4 + 256*20*4 = 53248 (sRed aliased in h1s);
  // + tail 528 -> 53776. 3x53776 = 161.3KB <= 163.8KB -> 3 blk/CU.
  __shared__ __align__(16) char sm[53776];
  const int b = blockIdx.x / 512;
  const int i = blockIdx.x - b * 512;
  knnconv_body<512, 256, 256, true, true, 512>(sm, pos + (size_t)b * 512 * 3,
                                               b, i, U, Wrel, b1, W2, b2,
                                               feat, rr);
}

// ---------------- fused gather + preproj (U = x[fi] @ W[:CIN] + b) ----------
template<int CIN, int HH>
__global__ __launch_bounds__(HH)
void gp_kernel(const float* __restrict__ X, const float* __restrict__ posPrev,
               const int* __restrict__ fi, int Nprev, int M,
               const float* __restrict__ W, const float* __restrict__ bias,
               float* __restrict__ U, float* __restrict__ posDst) {
  const int row = blockIdx.x;
  const int b = row / M;
  const int tid = threadIdx.x;
  const int j = fi[row];
  __shared__ float sx[CIN];
  if (tid < CIN) sx[tid] = X[((size_t)b * Nprev + j) * CIN + tid];
  if (tid < 3) posDst[(size_t)row * 3 + tid] = posPrev[((size_t)b * Nprev + j) * 3 + tid];
  __syncthreads();
  float a = bias[tid];
  for (int f = 0; f < CIN; f++) a = fmaf(sx[f], W[f * HH + tid], a);
  U[(size_t)row * HH + tid] = a;
}

// ---------------- classifier/defense heads (feat precomputed) ---------------
__global__ __launch_bounds__(256) void head_kernel(
    const float* __restrict__ feat,
    const float* __restrict__ Wc1, const float* __restrict__ bc1,
    const float* __restrict__ Wc2, const float* __restrict__ bc2,
    const float* __restrict__ Wc3, const float* __restrict__ bc3,
    const float* __restrict__ Wd1, const float* __restrict__ bd1,
    const float* __restrict__ Wd2, const float* __restrict__ bd2,
    float* __restrict__ out) {
  const int b = blockIdx.x, tid = threadIdx.x;
  __shared__ float sf[256], sh[256], sh2[256], shd[256], sl[48];
  sf[tid] = feat[b * 256 + tid];
  __syncthreads();
  float a = bc1[tid], ad = bd1[tid];
  for (int f = 0; f < 256; f++) {
    const float fv = sf[f];
    a  = fmaf(fv, Wc1[f * 256 + tid], a);
    ad = fmaf(fv, Wd1[f * 256 + tid], ad);
  }
  sh[tid] = fmaxf(a, 0.f);
  shd[tid] = fmaxf(ad, 0.f);
  __syncthreads();
  float a2 = bc2[tid];
  for (int f = 0; f < 256; f++) a2 = fmaf(sh[f], Wc2[f * 256 + tid], a2);
  sh2[tid] = fmaxf(a2, 0.f);
  __syncthreads();
  if (tid < 40) {
    float l = bc3[tid];
    for (int f = 0; f < 256; f++) l = fmaf(sh2[f], Wc3[f * 40 + tid], l);
    sl[tid] = l;
  }
  if (tid >= 64 && tid < 66) {
    const int q = tid - 64;
    float l = bd2[q];
    for (int f = 0; f < 256; f++) l = fmaf(shd[f], Wd2[f * 2 + q], l);
    sl[40 + q] = l;
  }
  __syncthreads();
  if (tid == 0) {
    float m0 = sl[0];
    for (int q = 1; q < 40; q++) m0 = fmaxf(m0, sl[q]);
    float s = 0.f;
    for (int q = 0; q < 40; q++) s += expf(sl[q] - m0);
    const float ls = logf(s);
    for (int q = 0; q < 40; q++) out[b * 40 + q] = sl[q] - m0 - ls;
    const float m1 = fmaxf(sl[40], sl[41]);
    const float s1 = expf(sl[40] - m1) + expf(sl[41] - m1);
    const float ls1 = logf(s1);
    out[320 + b * 2 + 0] = sl[40] - m1 - ls1;
    out[320 + b * 2 + 1] = sl[41] - m1 - ls1;
  }
}

// ---------------------------------------------------------------------------
extern "C" void kernel_launch(void* const* d_in, const int* in_sizes, int n_in,
                              void* d_out, int out_size, void* d_ws, size_t ws_size,
                              hipStream_t stream) {
  (void)in_sizes; (void)n_in; (void)out_size; (void)ws_size;
  const float* pos = (const float*)d_in[0];
  const float* W1a = (const float*)d_in[1];  const float* b1a = (const float*)d_in[2];
  const float* W1b = (const float*)d_in[3];  const float* b1b = (const float*)d_in[4];
  const float* W2a = (const float*)d_in[5];  const float* b2a = (const float*)d_in[6];
  const float* W2b = (const float*)d_in[7];  const float* b2b = (const float*)d_in[8];
  const float* W3a = (const float*)d_in[9];  const float* b3a = (const float*)d_in[10];
  const float* W3b = (const float*)d_in[11]; const float* b3b = (const float*)d_in[12];
  const float* Wc1 = (const float*)d_in[13]; const float* bc1 = (const float*)d_in[14];
  const float* Wc2 = (const float*)d_in[15]; const float* bc2 = (const float*)d_in[16];
  const float* Wc3 = (const float*)d_in[17]; const float* bc3 = (const float*)d_in[18];
  const float* Wd1 = (const float*)d_in[19]; const float* bd1 = (const float*)d_in[20];
  const float* Wd2 = (const float*)d_in[21]; const float* bd2 = (const float*)d_in[22];
  float* out = (float*)d_out;

  char* w = (char*)d_ws;
  auto alloc = [&](size_t bytes) -> void* {
    void* p = (void*)w;
    w += (bytes + 255) & ~(size_t)255;
    return p;
  };
  int*   fi1  = (int*)  alloc((size_t)NB*2048*4);
  float* x1   = (float*)alloc((size_t)NB*4096*64*4);
  float* pos2 = (float*)alloc((size_t)NB*2048*3*4);
  float* U2   = (float*)alloc((size_t)NB*2048*128*4);
  float* x2   = (float*)alloc((size_t)NB*2048*128*4);
  int*   fi2  = (int*)  alloc((size_t)NB*512*4);
  float* pos3 = (float*)alloc((size_t)NB*512*3*4);
  float* U3   = (float*)alloc((size_t)NB*512*256*4);
  float* feat = (float*)alloc((size_t)NB*256*4);

  // feat = 0 (atomicMax target; all pooled values are >= 0 post-relu)
  hipMemsetAsync(feat, 0, (size_t)NB * 256 * 4, stream);

  // stage 1: {fps1 || knn1+conv1}  (both depend only on pos)
  stage1_kernel<<<NB + NB * 4096, 512, 0, stream>>>(
      pos, 0.2 * 0.2, fi1, W1a, b1a, W1b, b1b, x1);

  // gather1 + preproj2 (U2 = x1[fi1] @ W2a[:64] + b2a)
  gp_kernel<64, 128><<<NB * 2048, 128, 0, stream>>>(
      x1, pos, fi1, 4096, 2048, W2a, b2a, U2, pos2);

  // stage 2: {fps2 || knn2+conv2}
  stage2_kernel<<<NB + NB * 2048, 512, 0, stream>>>(
      pos2, 0.4 * 0.4, fi2, U2, W2a + (size_t)64 * 128, b2a, W2b, b2b, x2);

  // gather2 + preproj3
  gp_kernel<128, 256><<<NB * 512, 256, 0, stream>>>(
      x2, pos2, fi2, 2048, 512, W3a, b3a, U3, pos3);

  // stage 3: knn3+conv3 with fused global max-pool (atomicMax into feat)
  stage3_kernel<<<NB * 512, 512, 0, stream>>>(
      pos3, 1.0, U3, W3a + (size_t)128 * 256, b3a, W3b, b3b, feat);

  // heads
  head_kernel<<<NB, 256, 0, stream>>>(feat, Wc1, bc1, Wc2, bc2, Wc3, bc3,
                                      Wd1, bd1, Wd2, bd2, out);
}